// Round 10
// baseline (302.431 us; speedup 1.0000x reference)
//
#include <hip/hip_runtime.h>

#define NODES 100000
#define EDGES 1600000
#define BSH 8
#define NBUCK ((NODES + 255) >> BSH)   // 391
#define CHUNK 4096
#define LMAX 8192
#define MCHUNKS ((NODES + 31) / 32)    // 3125
// IN_F = HID_F = 128, OUT_F = 64

using bf16x8 = __attribute__((ext_vector_type(8))) short;
using f32x4  = __attribute__((ext_vector_type(4))) float;
using f32x2  = __attribute__((ext_vector_type(2))) float;

__device__ __forceinline__ unsigned short f2b(float f) {
    unsigned u = __builtin_bit_cast(unsigned, f);
    unsigned r = (u + 0x7FFFu + ((u >> 16) & 1u)) >> 16;
    return (unsigned short)r;
}

// unpack 8 fp8 (uint2) and accumulate into a[0..7]
__device__ __forceinline__ void add_fp8x8(float* a, uint2 v) {
    f32x2 p0 = __builtin_amdgcn_cvt_pk_f32_fp8((int)v.x, false);
    f32x2 p1 = __builtin_amdgcn_cvt_pk_f32_fp8((int)v.x, true);
    f32x2 p2 = __builtin_amdgcn_cvt_pk_f32_fp8((int)v.y, false);
    f32x2 p3 = __builtin_amdgcn_cvt_pk_f32_fp8((int)v.y, true);
    a[0] += p0[0]; a[1] += p0[1]; a[2] += p1[0]; a[3] += p1[1];
    a[4] += p2[0]; a[5] += p2[1]; a[6] += p3[0]; a[7] += p3[1];
}

// ---------------- CSR build (no fine-grained global atomics) ----------------

__global__ __launch_bounds__(256) void bhist_kernel(const int* __restrict__ dst,
                                                    int* __restrict__ bucket_cnt) {
    __shared__ int lcnt[512];
    int t = threadIdx.x;
    lcnt[t] = 0; lcnt[t + 256] = 0;
    __syncthreads();
    int base = blockIdx.x * 16384;
    int n = EDGES - base;
    if (n > 16384) n = 16384;
    const int4* d4 = reinterpret_cast<const int4*>(dst + base);
    for (int i = t; i < (n >> 2); i += 256) {
        int4 d = d4[i];
        atomicAdd(&lcnt[d.x >> BSH], 1);
        atomicAdd(&lcnt[d.y >> BSH], 1);
        atomicAdd(&lcnt[d.z >> BSH], 1);
        atomicAdd(&lcnt[d.w >> BSH], 1);
    }
    for (int i = (n & ~3) + t; i < n; i += 256) atomicAdd(&lcnt[dst[base + i] >> BSH], 1);
    __syncthreads();
    if (lcnt[t]) atomicAdd(&bucket_cnt[t], lcnt[t]);
    if (lcnt[t + 256]) atomicAdd(&bucket_cnt[t + 256], lcnt[t + 256]);
}

__global__ void bscan_kernel(const int* __restrict__ bucket_cnt, int* __restrict__ bucket_off,
                             int* __restrict__ gcursor, int* __restrict__ row_ptr) {
    __shared__ int sh[512];
    int t = threadIdx.x;
    int v = (t < NBUCK) ? bucket_cnt[t] : 0;
    sh[t] = v;
    __syncthreads();
    for (int off = 1; off < 512; off <<= 1) {
        int x = (t >= off) ? sh[t - off] : 0;
        __syncthreads();
        sh[t] += x;
        __syncthreads();
    }
    int excl = sh[t] - v;
    if (t < NBUCK) { bucket_off[t] = excl; gcursor[t] = excl; }
    if (t == NBUCK) bucket_off[t] = EDGES;
    if (t == 0) row_ptr[NODES] = EDGES;
}

// Bin edges by coarse bucket; write packed (dst&255)<<24|src runs.
__global__ __launch_bounds__(256) void binscat_kernel(
    const int* __restrict__ src, const int* __restrict__ dst,
    int* __restrict__ gcursor, unsigned* __restrict__ pairs) {
    __shared__ int cnt[512];
    __shared__ int scn[512];
    __shared__ int gbs[512];
    __shared__ int cur[512];
    __shared__ uint2 stage[CHUNK];
    int t = threadIdx.x;
    int base = blockIdx.x * CHUNK;
    int n = EDGES - base;
    if (n > CHUNK) n = CHUNK;

    cnt[t] = 0; cnt[t + 256] = 0;
    __syncthreads();

    uint2 my[16];
#pragma unroll
    for (int i = 0; i < 16; ++i) {
        int idx = t + i * 256;
        if (idx < n) {
            int d = dst[base + idx];
            int s = src[base + idx];
            my[i] = make_uint2((unsigned)d, (unsigned)s);
            atomicAdd(&cnt[d >> BSH], 1);
        } else {
            my[i] = make_uint2(0xFFFFFFFFu, 0);
        }
    }
    __syncthreads();
    scn[t] = cnt[t]; scn[t + 256] = cnt[t + 256];
    __syncthreads();
    for (int off = 1; off < 512; off <<= 1) {
        int a0 = (t >= off) ? scn[t - off] : 0;
        int a1 = (t + 256 >= off) ? scn[t + 256 - off] : 0;
        __syncthreads();
        scn[t] += a0; scn[t + 256] += a1;
        __syncthreads();
    }
    cur[t] = scn[t] - cnt[t];
    cur[t + 256] = scn[t + 256] - cnt[t + 256];
    __syncthreads();
#pragma unroll
    for (int i = 0; i < 16; ++i) {
        if (my[i].x != 0xFFFFFFFFu) {
            int b = (int)(my[i].x >> BSH);
            int p = atomicAdd(&cur[b], 1);
            stage[p] = my[i];
        }
    }
    for (int b2 = t; b2 < 512; b2 += 256) {
        int c = cnt[b2];
        gbs[b2] = (c > 0 && b2 < NBUCK) ? atomicAdd(&gcursor[b2], c) : 0;
    }
    __syncthreads();
    for (int idx = t; idx < n; idx += 256) {
        uint2 p = stage[idx];
        int b = (int)(p.x >> BSH);
        int excl = scn[b] - cnt[b];
        pairs[gbs[b] + idx - excl] = ((p.x & 255u) << 24) | p.y;
    }
}

__global__ __launch_bounds__(256) void localsort_kernel(
    const unsigned* __restrict__ pairs, const int* __restrict__ bucket_off,
    int* __restrict__ row_ptr, int* __restrict__ src_sorted) {
    __shared__ int cnt[256];
    __shared__ int cur[256];
    __shared__ int stage[LMAX];
    int b = blockIdx.x;
    int t = threadIdx.x;
    int node0 = b << BSH;
    int pbeg = bucket_off[b], pend = bucket_off[b + 1];
    int n = pend - pbeg;
    cnt[t] = 0;
    __syncthreads();
    for (int e = pbeg + t; e < pend; e += 256)
        atomicAdd(&cnt[(int)(pairs[e] >> 24)], 1);
    __syncthreads();
    int v = cnt[t];
    cur[t] = v;
    __syncthreads();
    for (int off = 1; off < 256; off <<= 1) {
        int x = (t >= off) ? cur[t - off] : 0;
        __syncthreads();
        cur[t] += x;
        __syncthreads();
    }
    int excl = cur[t] - v;
    int node = node0 + t;
    if (node < NODES) row_ptr[node] = pbeg + excl;
    cur[t] = excl;
    __syncthreads();
    if (n <= LMAX) {
        for (int e = pbeg + t; e < pend; e += 256) {
            unsigned p = pairs[e];
            int pos = atomicAdd(&cur[(int)(p >> 24)], 1);
            stage[pos] = (int)(p & 0xFFFFFFu);
        }
        __syncthreads();
        for (int i = t; i < n; i += 256) src_sorted[pbeg + i] = stage[i];
    } else {
        for (int e = pbeg + t; e < pend; e += 256) {
            unsigned p = pairs[e];
            int pos = atomicAdd(&cur[(int)(p >> 24)], 1);
            src_sorted[pbeg + pos] = (int)(p & 0xFFFFFFu);
        }
    }
}

// ---------------- conversions (features->bf16+fp8, weights->bf16^T) ----------------

__global__ void conv_kernel(const float* __restrict__ in, unsigned short* __restrict__ outb,
                            unsigned char* __restrict__ outq, int n4,
                            const float* __restrict__ W1s, const float* __restrict__ W1n,
                            const float* __restrict__ W2s, const float* __restrict__ W2n,
                            unsigned short* __restrict__ Wt1s, unsigned short* __restrict__ Wt1n,
                            unsigned short* __restrict__ Wt2s, unsigned short* __restrict__ Wt2n) {
    int i = blockIdx.x * 256 + threadIdx.x;
    if (i < n4) {
        float4 v = reinterpret_cast<const float4*>(in)[i];
        uint2 o;
        o.x = (unsigned)f2b(v.x) | ((unsigned)f2b(v.y) << 16);
        o.y = (unsigned)f2b(v.z) | ((unsigned)f2b(v.w) << 16);
        reinterpret_cast<uint2*>(outb)[i] = o;
        int pk = __builtin_amdgcn_cvt_pk_fp8_f32(v.x, v.y, 0, false);
        pk = __builtin_amdgcn_cvt_pk_fp8_f32(v.z, v.w, pk, true);
        reinterpret_cast<unsigned*>(outq)[i] = (unsigned)pk;
    }
    if (i < 16384) {
        int k = i >> 7, n = i & 127;
        Wt1s[n * 128 + k] = f2b(W1s[i]);
        Wt1n[n * 128 + k] = f2b(W1n[i]);
    }
    if (i < 8192) {
        int k = i >> 6, n = i & 63;
        Wt2s[n * 128 + k] = f2b(W2s[i]);
        Wt2n[n * 128 + k] = f2b(W2n[i]);
    }
}

// ---------------- Mean aggregation, fp8 gather ----------------
// agg128: one wave/node; 16 lanes/row x 8B fp8 (8 feats), 4 groups, unroll 2.

__global__ __launch_bounds__(256) void agg128_fp8(
    const unsigned char* __restrict__ xq, const int* __restrict__ row_ptr,
    const int* __restrict__ srcs, unsigned short* __restrict__ out) {
    int w = (blockIdx.x * 256 + threadIdx.x) >> 6;
    int lane = threadIdx.x & 63;
    if (w >= NODES) return;
    int g = lane >> 4;
    int sl = lane & 15;
    int beg = row_ptr[w], end = row_ptr[w + 1];

    float a0[8], a1[8];
#pragma unroll
    for (int i = 0; i < 8; ++i) { a0[i] = 0.f; a1[i] = 0.f; }

    const unsigned char* xs = xq + sl * 8;
    int e = beg + g;
    for (; e + 4 < end; e += 8) {
        int s0 = srcs[e];
        int s1 = srcs[e + 4];
        uint2 v0 = *reinterpret_cast<const uint2*>(xs + (size_t)s0 * 128);
        uint2 v1 = *reinterpret_cast<const uint2*>(xs + (size_t)s1 * 128);
        add_fp8x8(a0, v0);
        add_fp8x8(a1, v1);
    }
    if (e < end) {
        int s0 = srcs[e];
        uint2 v0 = *reinterpret_cast<const uint2*>(xs + (size_t)s0 * 128);
        add_fp8x8(a0, v0);
    }
#pragma unroll
    for (int i = 0; i < 8; ++i) {
        float s = a0[i] + a1[i];
        s += __shfl_xor(s, 16, 64);
        s += __shfl_xor(s, 32, 64);
        a0[i] = s;
    }
    if (g == 0) {
        float inv = 1.0f / fmaxf((float)(end - beg), 1.0f);
        uint4 o;
        o.x = (unsigned)f2b(a0[0] * inv) | ((unsigned)f2b(a0[1] * inv) << 16);
        o.y = (unsigned)f2b(a0[2] * inv) | ((unsigned)f2b(a0[3] * inv) << 16);
        o.z = (unsigned)f2b(a0[4] * inv) | ((unsigned)f2b(a0[5] * inv) << 16);
        o.w = (unsigned)f2b(a0[6] * inv) | ((unsigned)f2b(a0[7] * inv) << 16);
        *reinterpret_cast<uint4*>(out + (size_t)w * 128 + sl * 8) = o;
    }
}

// agg64: one wave/node; 8 lanes/row x 8B fp8, 8 groups, unroll 2. out += mean.
__global__ __launch_bounds__(256) void agg64_add8(
    const unsigned char* __restrict__ xq, const int* __restrict__ row_ptr,
    const int* __restrict__ srcs, float* __restrict__ out) {
    int w = (blockIdx.x * 256 + threadIdx.x) >> 6;
    int lane = threadIdx.x & 63;
    if (w >= NODES) return;
    int g = lane >> 3;
    int sl = lane & 7;
    int beg = row_ptr[w], end = row_ptr[w + 1];

    float a0[8], a1[8];
#pragma unroll
    for (int i = 0; i < 8; ++i) { a0[i] = 0.f; a1[i] = 0.f; }

    const unsigned char* xs = xq + sl * 8;
    int e = beg + g;
    for (; e + 8 < end; e += 16) {
        int s0 = srcs[e];
        int s1 = srcs[e + 8];
        uint2 v0 = *reinterpret_cast<const uint2*>(xs + (size_t)s0 * 64);
        uint2 v1 = *reinterpret_cast<const uint2*>(xs + (size_t)s1 * 64);
        add_fp8x8(a0, v0);
        add_fp8x8(a1, v1);
    }
    if (e < end) {
        int s0 = srcs[e];
        uint2 v0 = *reinterpret_cast<const uint2*>(xs + (size_t)s0 * 64);
        add_fp8x8(a0, v0);
    }
#pragma unroll
    for (int i = 0; i < 8; ++i) {
        float s = a0[i] + a1[i];
        s += __shfl_xor(s, 8, 64);
        s += __shfl_xor(s, 16, 64);
        s += __shfl_xor(s, 32, 64);
        a0[i] = s;
    }
    if (g == 0) {
        float inv = 1.0f / fmaxf((float)(end - beg), 1.0f);
        float* op = out + (size_t)w * 64 + sl * 8;
        float4 p0 = *reinterpret_cast<float4*>(op);
        float4 p1 = *reinterpret_cast<float4*>(op + 4);
        p0.x += a0[0] * inv; p0.y += a0[1] * inv;
        p0.z += a0[2] * inv; p0.w += a0[3] * inv;
        p1.x += a0[4] * inv; p1.y += a0[5] * inv;
        p1.z += a0[6] * inv; p1.w += a0[7] * inv;
        *reinterpret_cast<float4*>(op) = p0;
        *reinterpret_cast<float4*>(op + 4) = p1;
    }
}

// ---------------- Fused MLP: one 32-row chunk per block, single barrier ----------------
// x1 = relu(feat@W1s + agg@W1n + b1) (LDS only); x1h8 = fp8(x1@W2n);
// outp = x1@W2s + b2. A-loads issued first (longest latency), weights from
// L2-hot 96KB re-loaded per block; block-level parallelism hides barriers.

__global__ __launch_bounds__(256) void fused_mlp(
    const unsigned short* __restrict__ featb, const unsigned short* __restrict__ agg,
    const unsigned short* __restrict__ Wt1s, const unsigned short* __restrict__ Wt1n,
    const float* __restrict__ b1, const unsigned short* __restrict__ Wt2s,
    const unsigned short* __restrict__ Wt2n, const float* __restrict__ b2,
    unsigned char* __restrict__ x1h8, float* __restrict__ outp) {
    __shared__ __align__(16) unsigned short x1t[32 * 136];
    int wid = threadIdx.x >> 6, lane = threadIdx.x & 63;
    int l15 = lane & 15, quad = lane >> 4;
    int rbase = blockIdx.x * 32;

    // A-loads first: longest-latency (featb/agg1 are HBM/L3-resident)
    bf16x8 Af[2][4], Aa[2][4];
#pragma unroll
    for (int rg = 0; rg < 2; ++rg) {
        int r = rbase + rg * 16 + l15;
        if (r >= NODES) r = NODES - 1;
        const unsigned short* fp = featb + (size_t)r * 128 + quad * 8;
        const unsigned short* ap = agg + (size_t)r * 128 + quad * 8;
#pragma unroll
        for (int k = 0; k < 4; ++k) {
            Af[rg][k] = *reinterpret_cast<const bf16x8*>(fp + k * 32);
            Aa[rg][k] = *reinterpret_cast<const bf16x8*>(ap + k * 32);
        }
    }

    // weight strips (L2-hot): W1 cols [wid*32, wid*32+32), W2 cols [wid*16, +16)
    bf16x8 B1s[2][4], B1n[2][4];
#pragma unroll
    for (int nt = 0; nt < 2; ++nt) {
        int col = wid * 32 + nt * 16 + l15;
#pragma unroll
        for (int k = 0; k < 4; ++k) {
            B1s[nt][k] = *reinterpret_cast<const bf16x8*>(Wt1s + (size_t)col * 128 + k * 32 + quad * 8);
            B1n[nt][k] = *reinterpret_cast<const bf16x8*>(Wt1n + (size_t)col * 128 + k * 32 + quad * 8);
        }
    }
    bf16x8 B2s[4], B2n[4];
    int col2 = wid * 16 + l15;
#pragma unroll
    for (int k = 0; k < 4; ++k) {
        B2s[k] = *reinterpret_cast<const bf16x8*>(Wt2s + (size_t)col2 * 128 + k * 32 + quad * 8);
        B2n[k] = *reinterpret_cast<const bf16x8*>(Wt2n + (size_t)col2 * 128 + k * 32 + quad * 8);
    }
    float bv1[2];
    bv1[0] = b1[wid * 32 + l15];
    bv1[1] = b1[wid * 32 + 16 + l15];
    float bv2 = b2[col2];

    // phase 1: x1 tile
    f32x4 acc[2][2];
#pragma unroll
    for (int rg = 0; rg < 2; ++rg)
#pragma unroll
        for (int nt = 0; nt < 2; ++nt) acc[rg][nt] = {0.f, 0.f, 0.f, 0.f};
#pragma unroll
    for (int k = 0; k < 4; ++k)
#pragma unroll
        for (int nt = 0; nt < 2; ++nt)
#pragma unroll
            for (int rg = 0; rg < 2; ++rg) {
                acc[rg][nt] = __builtin_amdgcn_mfma_f32_16x16x32_bf16(Af[rg][k], B1s[nt][k], acc[rg][nt], 0, 0, 0);
                acc[rg][nt] = __builtin_amdgcn_mfma_f32_16x16x32_bf16(Aa[rg][k], B1n[nt][k], acc[rg][nt], 0, 0, 0);
            }
#pragma unroll
    for (int nt = 0; nt < 2; ++nt)
#pragma unroll
        for (int rg = 0; rg < 2; ++rg)
#pragma unroll
            for (int rr = 0; rr < 4; ++rr) {
                float v = fmaxf(acc[rg][nt][rr] + bv1[nt], 0.f);
                x1t[(rg * 16 + quad * 4 + rr) * 136 + wid * 32 + nt * 16 + l15] = f2b(v);
            }
    __syncthreads();

    // phase 2: layer-2 GEMMs from LDS x1 tile
    f32x4 acc2s[2], acc2n[2];
#pragma unroll
    for (int rg = 0; rg < 2; ++rg) { acc2s[rg] = {0.f, 0.f, 0.f, 0.f}; acc2n[rg] = {0.f, 0.f, 0.f, 0.f}; }
#pragma unroll
    for (int k = 0; k < 4; ++k)
#pragma unroll
        for (int rg = 0; rg < 2; ++rg) {
            bf16x8 a = *reinterpret_cast<const bf16x8*>(&x1t[(rg * 16 + l15) * 136 + k * 32 + quad * 8]);
            acc2s[rg] = __builtin_amdgcn_mfma_f32_16x16x32_bf16(a, B2s[k], acc2s[rg], 0, 0, 0);
            acc2n[rg] = __builtin_amdgcn_mfma_f32_16x16x32_bf16(a, B2n[k], acc2n[rg], 0, 0, 0);
        }
#pragma unroll
    for (int rg = 0; rg < 2; ++rg)
#pragma unroll
        for (int rr = 0; rr < 4; ++rr) {
            int row = rbase + rg * 16 + quad * 4 + rr;
            if (row < NODES) {
                float vn = acc2n[rg][rr];
                int pk = __builtin_amdgcn_cvt_pk_fp8_f32(vn, vn, 0, false);
                x1h8[(size_t)row * 64 + col2] = (unsigned char)(pk & 0xFF);
                outp[(size_t)row * 64 + col2] = acc2s[rg][rr] + bv2;
            }
        }
}

// ---------------- launch ----------------

extern "C" void kernel_launch(void* const* d_in, const int* in_sizes, int n_in,
                              void* d_out, int out_size, void* d_ws, size_t ws_size,
                              hipStream_t stream) {
    const float* features = (const float*)d_in[0];
    const int* esrc = (const int*)d_in[1];
    const int* edst = (const int*)d_in[2];
    const float* W1s = (const float*)d_in[3];
    const float* W1n = (const float*)d_in[4];
    const float* b1  = (const float*)d_in[5];
    const float* W2s = (const float*)d_in[6];
    const float* W2n = (const float*)d_in[7];
    const float* b2  = (const float*)d_in[8];
    float* out = (float*)d_out;

    char* ws = (char*)d_ws;
    size_t off = 0;
    auto alloc = [&](size_t bytes) {
        void* p = ws + off;
        off += (bytes + 255) & ~(size_t)255;
        return p;
    };
    int* bucket_cnt = (int*)alloc(512 * 4);
    int* bucket_off = (int*)alloc(512 * 4);
    int* gcursor    = (int*)alloc(512 * 4);
    int* row_ptr    = (int*)alloc((size_t)(NODES + 1) * 4);
    int* src_sorted = (int*)alloc((size_t)EDGES * 4);
    unsigned* pairs = (unsigned*)alloc((size_t)EDGES * 4);
    unsigned short* featb = (unsigned short*)alloc((size_t)NODES * 128 * 2);
    unsigned char*  feat8 = (unsigned char*)alloc((size_t)NODES * 128);
    unsigned short* agg1  = (unsigned short*)alloc((size_t)NODES * 128 * 2);
    unsigned char*  x1h8  = (unsigned char*)alloc((size_t)NODES * 64);
    unsigned short* Wt1s  = (unsigned short*)alloc(16384 * 2);
    unsigned short* Wt1n  = (unsigned short*)alloc(16384 * 2);
    unsigned short* Wt2s  = (unsigned short*)alloc(8192 * 2);
    unsigned short* Wt2n  = (unsigned short*)alloc(8192 * 2);

    // conversions (features -> bf16+fp8; weights -> bf16 transposed)
    conv_kernel<<<(NODES * 128 / 4 + 255) / 256, 256, 0, stream>>>(
        features, featb, feat8, NODES * 128 / 4, W1s, W1n, W2s, W2n, Wt1s, Wt1n, Wt2s, Wt2n);

    // CSR build: coarse hist -> bucket scan -> bucket bin -> per-bucket sort
    hipMemsetAsync(bucket_cnt, 0, 512 * 4, stream);
    bhist_kernel<<<(EDGES + 16383) / 16384, 256, 0, stream>>>(edst, bucket_cnt);
    bscan_kernel<<<1, 512, 0, stream>>>(bucket_cnt, bucket_off, gcursor, row_ptr);
    binscat_kernel<<<(EDGES + CHUNK - 1) / CHUNK, 256, 0, stream>>>(esrc, edst, gcursor, pairs);
    localsort_kernel<<<NBUCK, 256, 0, stream>>>(pairs, bucket_off, row_ptr, src_sorted);

    // layer 1 aggregation (fp8 gather -> bf16 agg matrix)
    agg128_fp8<<<(NODES * 64 + 255) / 256, 256, 0, stream>>>(feat8, row_ptr, src_sorted, agg1);

    // fused MLP: x1 in LDS; writes x1h fp8 + out (self part + bias)
    fused_mlp<<<MCHUNKS, 256, 0, stream>>>(featb, agg1, Wt1s, Wt1n, b1, Wt2s, Wt2n, b2, x1h8, out);

    // out += mean-neigh(x1h)
    agg64_add8<<<(NODES * 64 + 255) / 256, 256, 0, stream>>>(x1h8, row_ptr, src_sorted, out);
}

// Round 11
// 283.844 us; speedup vs baseline: 1.0655x; 1.0655x over previous
//
#include <hip/hip_runtime.h>

#define NODES 100000
#define EDGES 1600000
#define BSH 8
#define NBUCK ((NODES + 255) >> BSH)   // 391
#define CHUNK 4096
#define LMAX 8192
#define MCHUNKS ((NODES + 31) / 32)    // 3125
// IN_F = HID_F = 128, OUT_F = 64

using bf16x8 = __attribute__((ext_vector_type(8))) short;
using f32x4  = __attribute__((ext_vector_type(4))) float;
using f32x2  = __attribute__((ext_vector_type(2))) float;

__device__ __forceinline__ unsigned short f2b(float f) {
    unsigned u = __builtin_bit_cast(unsigned, f);
    unsigned r = (u + 0x7FFFu + ((u >> 16) & 1u)) >> 16;
    return (unsigned short)r;
}

// unpack 8 fp8 (uint2) and accumulate into a[0..7]
__device__ __forceinline__ void add_fp8x8(float* a, uint2 v) {
    f32x2 p0 = __builtin_amdgcn_cvt_pk_f32_fp8((int)v.x, false);
    f32x2 p1 = __builtin_amdgcn_cvt_pk_f32_fp8((int)v.x, true);
    f32x2 p2 = __builtin_amdgcn_cvt_pk_f32_fp8((int)v.y, false);
    f32x2 p3 = __builtin_amdgcn_cvt_pk_f32_fp8((int)v.y, true);
    a[0] += p0[0]; a[1] += p0[1]; a[2] += p1[0]; a[3] += p1[1];
    a[4] += p2[0]; a[5] += p2[1]; a[6] += p3[0]; a[7] += p3[1];
}

// ---------------- CSR build (no fine-grained global atomics) ----------------

__global__ __launch_bounds__(256) void bhist_kernel(const int* __restrict__ dst,
                                                    int* __restrict__ bucket_cnt) {
    __shared__ int lcnt[512];
    int t = threadIdx.x;
    lcnt[t] = 0; lcnt[t + 256] = 0;
    __syncthreads();
    int base = blockIdx.x * 16384;
    int n = EDGES - base;
    if (n > 16384) n = 16384;
    const int4* d4 = reinterpret_cast<const int4*>(dst + base);
    for (int i = t; i < (n >> 2); i += 256) {
        int4 d = d4[i];
        atomicAdd(&lcnt[d.x >> BSH], 1);
        atomicAdd(&lcnt[d.y >> BSH], 1);
        atomicAdd(&lcnt[d.z >> BSH], 1);
        atomicAdd(&lcnt[d.w >> BSH], 1);
    }
    for (int i = (n & ~3) + t; i < n; i += 256) atomicAdd(&lcnt[dst[base + i] >> BSH], 1);
    __syncthreads();
    if (lcnt[t]) atomicAdd(&bucket_cnt[t], lcnt[t]);
    if (lcnt[t + 256]) atomicAdd(&bucket_cnt[t + 256], lcnt[t + 256]);
}

__global__ void bscan_kernel(const int* __restrict__ bucket_cnt, int* __restrict__ bucket_off,
                             int* __restrict__ gcursor, int* __restrict__ row_ptr) {
    __shared__ int sh[512];
    int t = threadIdx.x;
    int v = (t < NBUCK) ? bucket_cnt[t] : 0;
    sh[t] = v;
    __syncthreads();
    for (int off = 1; off < 512; off <<= 1) {
        int x = (t >= off) ? sh[t - off] : 0;
        __syncthreads();
        sh[t] += x;
        __syncthreads();
    }
    int excl = sh[t] - v;
    if (t < NBUCK) { bucket_off[t] = excl; gcursor[t] = excl; }
    if (t == NBUCK) bucket_off[t] = EDGES;
    if (t == 0) row_ptr[NODES] = EDGES;
}

// Bin edges by coarse bucket; write packed (dst&255)<<24|src runs.
__global__ __launch_bounds__(256) void binscat_kernel(
    const int* __restrict__ src, const int* __restrict__ dst,
    int* __restrict__ gcursor, unsigned* __restrict__ pairs) {
    __shared__ int cnt[512];
    __shared__ int scn[512];
    __shared__ int gbs[512];
    __shared__ int cur[512];
    __shared__ uint2 stage[CHUNK];
    int t = threadIdx.x;
    int base = blockIdx.x * CHUNK;
    int n = EDGES - base;
    if (n > CHUNK) n = CHUNK;

    cnt[t] = 0; cnt[t + 256] = 0;
    __syncthreads();

    uint2 my[16];
#pragma unroll
    for (int i = 0; i < 16; ++i) {
        int idx = t + i * 256;
        if (idx < n) {
            int d = dst[base + idx];
            int s = src[base + idx];
            my[i] = make_uint2((unsigned)d, (unsigned)s);
            atomicAdd(&cnt[d >> BSH], 1);
        } else {
            my[i] = make_uint2(0xFFFFFFFFu, 0);
        }
    }
    __syncthreads();
    scn[t] = cnt[t]; scn[t + 256] = cnt[t + 256];
    __syncthreads();
    for (int off = 1; off < 512; off <<= 1) {
        int a0 = (t >= off) ? scn[t - off] : 0;
        int a1 = (t + 256 >= off) ? scn[t + 256 - off] : 0;
        __syncthreads();
        scn[t] += a0; scn[t + 256] += a1;
        __syncthreads();
    }
    cur[t] = scn[t] - cnt[t];
    cur[t + 256] = scn[t + 256] - cnt[t + 256];
    __syncthreads();
#pragma unroll
    for (int i = 0; i < 16; ++i) {
        if (my[i].x != 0xFFFFFFFFu) {
            int b = (int)(my[i].x >> BSH);
            int p = atomicAdd(&cur[b], 1);
            stage[p] = my[i];
        }
    }
    for (int b2 = t; b2 < 512; b2 += 256) {
        int c = cnt[b2];
        gbs[b2] = (c > 0 && b2 < NBUCK) ? atomicAdd(&gcursor[b2], c) : 0;
    }
    __syncthreads();
    for (int idx = t; idx < n; idx += 256) {
        uint2 p = stage[idx];
        int b = (int)(p.x >> BSH);
        int excl = scn[b] - cnt[b];
        pairs[gbs[b] + idx - excl] = ((p.x & 255u) << 24) | p.y;
    }
}

__global__ __launch_bounds__(256) void localsort_kernel(
    const unsigned* __restrict__ pairs, const int* __restrict__ bucket_off,
    int* __restrict__ row_ptr, int* __restrict__ src_sorted) {
    __shared__ int cnt[256];
    __shared__ int cur[256];
    __shared__ int stage[LMAX];
    int b = blockIdx.x;
    int t = threadIdx.x;
    int node0 = b << BSH;
    int pbeg = bucket_off[b], pend = bucket_off[b + 1];
    int n = pend - pbeg;
    cnt[t] = 0;
    __syncthreads();
    for (int e = pbeg + t; e < pend; e += 256)
        atomicAdd(&cnt[(int)(pairs[e] >> 24)], 1);
    __syncthreads();
    int v = cnt[t];
    cur[t] = v;
    __syncthreads();
    for (int off = 1; off < 256; off <<= 1) {
        int x = (t >= off) ? cur[t - off] : 0;
        __syncthreads();
        cur[t] += x;
        __syncthreads();
    }
    int excl = cur[t] - v;
    int node = node0 + t;
    if (node < NODES) row_ptr[node] = pbeg + excl;
    cur[t] = excl;
    __syncthreads();
    if (n <= LMAX) {
        for (int e = pbeg + t; e < pend; e += 256) {
            unsigned p = pairs[e];
            int pos = atomicAdd(&cur[(int)(p >> 24)], 1);
            stage[pos] = (int)(p & 0xFFFFFFu);
        }
        __syncthreads();
        for (int i = t; i < n; i += 256) src_sorted[pbeg + i] = stage[i];
    } else {
        for (int e = pbeg + t; e < pend; e += 256) {
            unsigned p = pairs[e];
            int pos = atomicAdd(&cur[(int)(p >> 24)], 1);
            src_sorted[pbeg + pos] = (int)(p & 0xFFFFFFu);
        }
    }
}

// ---------------- conversions (features->bf16+fp8, weights->bf16^T) ----------------

__global__ void conv_kernel(const float* __restrict__ in, unsigned short* __restrict__ outb,
                            unsigned char* __restrict__ outq, int n4,
                            const float* __restrict__ W1s, const float* __restrict__ W1n,
                            const float* __restrict__ W2s, const float* __restrict__ W2n,
                            unsigned short* __restrict__ Wt1s, unsigned short* __restrict__ Wt1n,
                            unsigned short* __restrict__ Wt2s, unsigned short* __restrict__ Wt2n) {
    int i = blockIdx.x * 256 + threadIdx.x;
    if (i < n4) {
        float4 v = reinterpret_cast<const float4*>(in)[i];
        uint2 o;
        o.x = (unsigned)f2b(v.x) | ((unsigned)f2b(v.y) << 16);
        o.y = (unsigned)f2b(v.z) | ((unsigned)f2b(v.w) << 16);
        reinterpret_cast<uint2*>(outb)[i] = o;
        int pk = __builtin_amdgcn_cvt_pk_fp8_f32(v.x, v.y, 0, false);
        pk = __builtin_amdgcn_cvt_pk_fp8_f32(v.z, v.w, pk, true);
        reinterpret_cast<unsigned*>(outq)[i] = (unsigned)pk;
    }
    if (i < 16384) {
        int k = i >> 7, n = i & 127;
        Wt1s[n * 128 + k] = f2b(W1s[i]);
        Wt1n[n * 128 + k] = f2b(W1n[i]);
    }
    if (i < 8192) {
        int k = i >> 6, n = i & 63;
        Wt2s[n * 128 + k] = f2b(W2s[i]);
        Wt2n[n * 128 + k] = f2b(W2n[i]);
    }
}

// ---------------- Mean aggregation, fp8 gather ----------------
// agg128: one wave/node; 16 lanes/row x 8B fp8 (8 feats), 4 groups, unroll 2.

__global__ __launch_bounds__(256) void agg128_fp8(
    const unsigned char* __restrict__ xq, const int* __restrict__ row_ptr,
    const int* __restrict__ srcs, unsigned short* __restrict__ out) {
    int w = (blockIdx.x * 256 + threadIdx.x) >> 6;
    int lane = threadIdx.x & 63;
    if (w >= NODES) return;
    int g = lane >> 4;
    int sl = lane & 15;
    int beg = row_ptr[w], end = row_ptr[w + 1];

    float a0[8], a1[8];
#pragma unroll
    for (int i = 0; i < 8; ++i) { a0[i] = 0.f; a1[i] = 0.f; }

    const unsigned char* xs = xq + sl * 8;
    int e = beg + g;
    for (; e + 4 < end; e += 8) {
        int s0 = srcs[e];
        int s1 = srcs[e + 4];
        uint2 v0 = *reinterpret_cast<const uint2*>(xs + (size_t)s0 * 128);
        uint2 v1 = *reinterpret_cast<const uint2*>(xs + (size_t)s1 * 128);
        add_fp8x8(a0, v0);
        add_fp8x8(a1, v1);
    }
    if (e < end) {
        int s0 = srcs[e];
        uint2 v0 = *reinterpret_cast<const uint2*>(xs + (size_t)s0 * 128);
        add_fp8x8(a0, v0);
    }
#pragma unroll
    for (int i = 0; i < 8; ++i) {
        float s = a0[i] + a1[i];
        s += __shfl_xor(s, 16, 64);
        s += __shfl_xor(s, 32, 64);
        a0[i] = s;
    }
    if (g == 0) {
        float inv = 1.0f / fmaxf((float)(end - beg), 1.0f);
        uint4 o;
        o.x = (unsigned)f2b(a0[0] * inv) | ((unsigned)f2b(a0[1] * inv) << 16);
        o.y = (unsigned)f2b(a0[2] * inv) | ((unsigned)f2b(a0[3] * inv) << 16);
        o.z = (unsigned)f2b(a0[4] * inv) | ((unsigned)f2b(a0[5] * inv) << 16);
        o.w = (unsigned)f2b(a0[6] * inv) | ((unsigned)f2b(a0[7] * inv) << 16);
        *reinterpret_cast<uint4*>(out + (size_t)w * 128 + sl * 8) = o;
    }
}

// agg64: one wave/node; 8 lanes/row x 8B fp8, 8 groups, unroll 2. out += mean.
__global__ __launch_bounds__(256) void agg64_add8(
    const unsigned char* __restrict__ xq, const int* __restrict__ row_ptr,
    const int* __restrict__ srcs, float* __restrict__ out) {
    int w = (blockIdx.x * 256 + threadIdx.x) >> 6;
    int lane = threadIdx.x & 63;
    if (w >= NODES) return;
    int g = lane >> 3;
    int sl = lane & 7;
    int beg = row_ptr[w], end = row_ptr[w + 1];

    float a0[8], a1[8];
#pragma unroll
    for (int i = 0; i < 8; ++i) { a0[i] = 0.f; a1[i] = 0.f; }

    const unsigned char* xs = xq + sl * 8;
    int e = beg + g;
    for (; e + 8 < end; e += 16) {
        int s0 = srcs[e];
        int s1 = srcs[e + 8];
        uint2 v0 = *reinterpret_cast<const uint2*>(xs + (size_t)s0 * 64);
        uint2 v1 = *reinterpret_cast<const uint2*>(xs + (size_t)s1 * 64);
        add_fp8x8(a0, v0);
        add_fp8x8(a1, v1);
    }
    if (e < end) {
        int s0 = srcs[e];
        uint2 v0 = *reinterpret_cast<const uint2*>(xs + (size_t)s0 * 64);
        add_fp8x8(a0, v0);
    }
#pragma unroll
    for (int i = 0; i < 8; ++i) {
        float s = a0[i] + a1[i];
        s += __shfl_xor(s, 8, 64);
        s += __shfl_xor(s, 16, 64);
        s += __shfl_xor(s, 32, 64);
        a0[i] = s;
    }
    if (g == 0) {
        float inv = 1.0f / fmaxf((float)(end - beg), 1.0f);
        float* op = out + (size_t)w * 64 + sl * 8;
        float4 p0 = *reinterpret_cast<float4*>(op);
        float4 p1 = *reinterpret_cast<float4*>(op + 4);
        p0.x += a0[0] * inv; p0.y += a0[1] * inv;
        p0.z += a0[2] * inv; p0.w += a0[3] * inv;
        p1.x += a0[4] * inv; p1.y += a0[5] * inv;
        p1.z += a0[6] * inv; p1.w += a0[7] * inv;
        *reinterpret_cast<float4*>(op) = p0;
        *reinterpret_cast<float4*>(op + 4) = p1;
    }
}

// ---------------- Fused MLP: grid-stride + double-buffered LDS + A prefetch ----
// x1 = relu(feat@W1s + agg@W1n + b1) lives only in LDS; x1h8 = fp8(x1@W2n);
// outp = x1@W2s + b2. One barrier per chunk (buffer parity proves safety);
// next chunk's A fragments prefetched while phase2 runs.

__global__ __launch_bounds__(256, 2) void fused_mlp(
    const unsigned short* __restrict__ featb, const unsigned short* __restrict__ agg,
    const unsigned short* __restrict__ Wt1s, const unsigned short* __restrict__ Wt1n,
    const float* __restrict__ b1, const unsigned short* __restrict__ Wt2s,
    const unsigned short* __restrict__ Wt2n, const float* __restrict__ b2,
    unsigned char* __restrict__ x1h8, float* __restrict__ outp) {
    __shared__ __align__(16) unsigned short x1t[2][32 * 136];
    int wid = threadIdx.x >> 6, lane = threadIdx.x & 63;
    int l15 = lane & 15, quad = lane >> 4;

    // weight strips: W1 cols [wid*32, +32), W2 cols [wid*16, +16)
    bf16x8 B1s[2][4], B1n[2][4];
#pragma unroll
    for (int nt = 0; nt < 2; ++nt) {
        int col = wid * 32 + nt * 16 + l15;
#pragma unroll
        for (int k = 0; k < 4; ++k) {
            B1s[nt][k] = *reinterpret_cast<const bf16x8*>(Wt1s + (size_t)col * 128 + k * 32 + quad * 8);
            B1n[nt][k] = *reinterpret_cast<const bf16x8*>(Wt1n + (size_t)col * 128 + k * 32 + quad * 8);
        }
    }
    bf16x8 B2s[4], B2n[4];
    int col2 = wid * 16 + l15;
#pragma unroll
    for (int k = 0; k < 4; ++k) {
        B2s[k] = *reinterpret_cast<const bf16x8*>(Wt2s + (size_t)col2 * 128 + k * 32 + quad * 8);
        B2n[k] = *reinterpret_cast<const bf16x8*>(Wt2n + (size_t)col2 * 128 + k * 32 + quad * 8);
    }
    float bv1[2];
    bv1[0] = b1[wid * 32 + l15];
    bv1[1] = b1[wid * 32 + 16 + l15];
    float bv2 = b2[col2];

    auto loadA = [&](int cc, bf16x8 (&Afd)[2][4], bf16x8 (&Aad)[2][4]) {
#pragma unroll
        for (int rg = 0; rg < 2; ++rg) {
            int r = cc * 32 + rg * 16 + l15;
            if (r >= NODES) r = NODES - 1;
            const unsigned short* fp = featb + (size_t)r * 128 + quad * 8;
            const unsigned short* ap = agg + (size_t)r * 128 + quad * 8;
#pragma unroll
            for (int k = 0; k < 4; ++k) {
                Afd[rg][k] = *reinterpret_cast<const bf16x8*>(fp + k * 32);
                Aad[rg][k] = *reinterpret_cast<const bf16x8*>(ap + k * 32);
            }
        }
    };

    bf16x8 Af[2][4], Aa[2][4];
    int c = blockIdx.x;
    if (c < MCHUNKS) loadA(c, Af, Aa);
    int buf = 0;
    for (; c < MCHUNKS; c += gridDim.x) {
        int rbase = c * 32;
        int cn = c + (int)gridDim.x;

        // phase 1: consume Af/Aa
        f32x4 acc[2][2];
#pragma unroll
        for (int rg = 0; rg < 2; ++rg)
#pragma unroll
            for (int nt = 0; nt < 2; ++nt) acc[rg][nt] = {0.f, 0.f, 0.f, 0.f};
#pragma unroll
        for (int k = 0; k < 4; ++k)
#pragma unroll
            for (int nt = 0; nt < 2; ++nt)
#pragma unroll
                for (int rg = 0; rg < 2; ++rg) {
                    acc[rg][nt] = __builtin_amdgcn_mfma_f32_16x16x32_bf16(Af[rg][k], B1s[nt][k], acc[rg][nt], 0, 0, 0);
                    acc[rg][nt] = __builtin_amdgcn_mfma_f32_16x16x32_bf16(Aa[rg][k], B1n[nt][k], acc[rg][nt], 0, 0, 0);
                }

        // prefetch next chunk's A (overlaps LDS write + barrier + phase 2)
        bf16x8 Pf[2][4], Pa[2][4];
        if (cn < MCHUNKS) loadA(cn, Pf, Pa);

        // epilogue phase 1 -> LDS
#pragma unroll
        for (int nt = 0; nt < 2; ++nt)
#pragma unroll
            for (int rg = 0; rg < 2; ++rg)
#pragma unroll
                for (int rr = 0; rr < 4; ++rr) {
                    float v = fmaxf(acc[rg][nt][rr] + bv1[nt], 0.f);
                    x1t[buf][(rg * 16 + quad * 4 + rr) * 136 + wid * 32 + nt * 16 + l15] = f2b(v);
                }
        __syncthreads();

        // phase 2: layer-2 GEMMs from LDS x1 tile
        f32x4 acc2s[2], acc2n[2];
#pragma unroll
        for (int rg = 0; rg < 2; ++rg) { acc2s[rg] = {0.f, 0.f, 0.f, 0.f}; acc2n[rg] = {0.f, 0.f, 0.f, 0.f}; }
#pragma unroll
        for (int k = 0; k < 4; ++k)
#pragma unroll
            for (int rg = 0; rg < 2; ++rg) {
                bf16x8 a = *reinterpret_cast<const bf16x8*>(&x1t[buf][(rg * 16 + l15) * 136 + k * 32 + quad * 8]);
                acc2s[rg] = __builtin_amdgcn_mfma_f32_16x16x32_bf16(a, B2s[k], acc2s[rg], 0, 0, 0);
                acc2n[rg] = __builtin_amdgcn_mfma_f32_16x16x32_bf16(a, B2n[k], acc2n[rg], 0, 0, 0);
            }
#pragma unroll
        for (int rg = 0; rg < 2; ++rg)
#pragma unroll
            for (int rr = 0; rr < 4; ++rr) {
                int row = rbase + rg * 16 + quad * 4 + rr;
                if (row < NODES) {
                    float vn = acc2n[rg][rr];
                    int pk = __builtin_amdgcn_cvt_pk_fp8_f32(vn, vn, 0, false);
                    x1h8[(size_t)row * 64 + col2] = (unsigned char)(pk & 0xFF);
                    outp[(size_t)row * 64 + col2] = acc2s[rg][rr] + bv2;
                }
            }

        // rotate buffers / prefetched A
        buf ^= 1;
        if (cn < MCHUNKS) {
#pragma unroll
            for (int rg = 0; rg < 2; ++rg)
#pragma unroll
                for (int k = 0; k < 4; ++k) {
                    Af[rg][k] = Pf[rg][k];
                    Aa[rg][k] = Pa[rg][k];
                }
        }
    }
}

// ---------------- launch ----------------

extern "C" void kernel_launch(void* const* d_in, const int* in_sizes, int n_in,
                              void* d_out, int out_size, void* d_ws, size_t ws_size,
                              hipStream_t stream) {
    const float* features = (const float*)d_in[0];
    const int* esrc = (const int*)d_in[1];
    const int* edst = (const int*)d_in[2];
    const float* W1s = (const float*)d_in[3];
    const float* W1n = (const float*)d_in[4];
    const float* b1  = (const float*)d_in[5];
    const float* W2s = (const float*)d_in[6];
    const float* W2n = (const float*)d_in[7];
    const float* b2  = (const float*)d_in[8];
    float* out = (float*)d_out;

    char* ws = (char*)d_ws;
    size_t off = 0;
    auto alloc = [&](size_t bytes) {
        void* p = ws + off;
        off += (bytes + 255) & ~(size_t)255;
        return p;
    };
    int* bucket_cnt = (int*)alloc(512 * 4);
    int* bucket_off = (int*)alloc(512 * 4);
    int* gcursor    = (int*)alloc(512 * 4);
    int* row_ptr    = (int*)alloc((size_t)(NODES + 1) * 4);
    int* src_sorted = (int*)alloc((size_t)EDGES * 4);
    unsigned* pairs = (unsigned*)alloc((size_t)EDGES * 4);
    unsigned short* featb = (unsigned short*)alloc((size_t)NODES * 128 * 2);
    unsigned char*  feat8 = (unsigned char*)alloc((size_t)NODES * 128);
    unsigned short* agg1  = (unsigned short*)alloc((size_t)NODES * 128 * 2);
    unsigned char*  x1h8  = (unsigned char*)alloc((size_t)NODES * 64);
    unsigned short* Wt1s  = (unsigned short*)alloc(16384 * 2);
    unsigned short* Wt1n  = (unsigned short*)alloc(16384 * 2);
    unsigned short* Wt2s  = (unsigned short*)alloc(8192 * 2);
    unsigned short* Wt2n  = (unsigned short*)alloc(8192 * 2);

    // conversions (features -> bf16+fp8; weights -> bf16 transposed)
    conv_kernel<<<(NODES * 128 / 4 + 255) / 256, 256, 0, stream>>>(
        features, featb, feat8, NODES * 128 / 4, W1s, W1n, W2s, W2n, Wt1s, Wt1n, Wt2s, Wt2n);

    // CSR build: coarse hist -> bucket scan -> bucket bin -> per-bucket sort
    hipMemsetAsync(bucket_cnt, 0, 512 * 4, stream);
    bhist_kernel<<<(EDGES + 16383) / 16384, 256, 0, stream>>>(edst, bucket_cnt);
    bscan_kernel<<<1, 512, 0, stream>>>(bucket_cnt, bucket_off, gcursor, row_ptr);
    binscat_kernel<<<(EDGES + CHUNK - 1) / CHUNK, 256, 0, stream>>>(esrc, edst, gcursor, pairs);
    localsort_kernel<<<NBUCK, 256, 0, stream>>>(pairs, bucket_off, row_ptr, src_sorted);

    // layer 1 aggregation (fp8 gather -> bf16 agg matrix)
    agg128_fp8<<<(NODES * 64 + 255) / 256, 256, 0, stream>>>(feat8, row_ptr, src_sorted, agg1);

    // fused MLP: x1 in LDS; writes x1h fp8 + out (self part + bias)
    fused_mlp<<<1024, 256, 0, stream>>>(featb, agg1, Wt1s, Wt1n, b1, Wt2s, Wt2n, b2, x1h8, out);

    // out += mean-neigh(x1h)
    agg64_add8<<<(NODES * 64 + 255) / 256, 256, 0, stream>>>(x1h8, row_ptr, src_sorted, out);
}